// Round 1
// baseline (1477.371 us; speedup 1.0000x reference)
//
#include <hip/hip_runtime.h>
#include <hip/hip_fp16.h>
#include <stdint.h>

#define B_   16
#define T_   30
#define NF   480       // frames = B*T
#define NN   2048      // nodes
#define EE   32768     // edges
#define FIN  8
#define HID  64
#define TEMP 128
#define BLK  512
#define EPS  1e-5f

typedef unsigned int u32;
typedef unsigned short u16;

// ---------- helpers ----------
__device__ __forceinline__ u16 f2bf(float f) {           // RNE f32->bf16
  u32 u = __float_as_uint(f);
  u32 r = u + 0x7FFFu + ((u >> 16) & 1u);
  return (u16)(r >> 16);
}
__device__ __forceinline__ u32 pack2bf(float a, float b) {
  return (u32)f2bf(a) | ((u32)f2bf(b) << 16);
}
__device__ __forceinline__ float bflo(u32 w) { return __uint_as_float(w << 16); }
__device__ __forceinline__ float bfhi(u32 w) { return __uint_as_float(w & 0xFFFF0000u); }

// ---------- kernel A LDS layout (bytes) ----------
#define OFF_KEYS 0        // u32[2048]; also scan-aux u32[512]; also lenkeys
#define OFF_PERM 8192     // u16[2048]
#define OFF_DINV 12288    // f32[2048]
#define OFF_CNT  20480    // u32[2048] (cursor after scan)
#define OFF_SEG  28672    // u32[2049]
#define OFF_LENO 36872    // u16[2048]
#define OFF_XS   40968    // f32[2048*9]  (pad 9 vs bank conflicts)
#define OFF_W1   114704   // f32[512] (16B aligned)
#define OFF_S1   116752   // f32[64]
#define OFF_T1   117008   // f32[64]
#define LDS_A    147456   // phase A2 reuses [0,147456) as bf16[2048][36]

__device__ __forceinline__ void bitonic2048(u32* a, int t) {
  for (int k = 2; k <= NN; k <<= 1) {
    for (int j = k >> 1; j > 0; j >>= 1) {
      #pragma unroll 1
      for (int p = t; p < NN / 2; p += BLK) {
        int i = ((p & ~(j - 1)) << 1) | (p & (j - 1));
        int l = i | j;
        u32 x = a[i], y = a[l];
        bool up = ((i & k) == 0);
        if ((x > y) == up) { a[i] = y; a[l] = x; }
      }
      __syncthreads();
    }
  }
}

__global__ __launch_bounds__(BLK, 2) void kA(
    const float* __restrict__ x, const int* __restrict__ ei, const float* __restrict__ ew,
    const int* __restrict__ nid, const float* __restrict__ W1, const float* __restrict__ b1,
    const float* __restrict__ g1, const float* __restrict__ be1,
    const float* __restrict__ m1, const float* __restrict__ v1,
    u32* __restrict__ rec_g, u16* __restrict__ h1_g)
{
  extern __shared__ unsigned char smem[];
  const int g = blockIdx.x;
  const int t = threadIdx.x;
  const int*   eig  = ei  + (size_t)g * 2 * EE;
  const float* ewg  = ew  + (size_t)g * EE;
  const int*   nidg = nid + (size_t)g * NN;
  const float* xg   = x   + (size_t)g * NN * FIN;
  u32* recf = rec_g + (size_t)g * EE;
  u16* h1f  = h1_g  + (size_t)g * (2 * NN * 32);   // two 32-feat planes, bf16

  u32*  keys = (u32*)(smem + OFF_KEYS);
  u16*  perm = (u16*)(smem + OFF_PERM);
  float* dinv = (float*)(smem + OFF_DINV);
  u32*  cnt  = (u32*)(smem + OFF_CNT);
  u32*  seg  = (u32*)(smem + OFF_SEG);
  u16*  leno = (u16*)(smem + OFF_LENO);
  float* xs  = (float*)(smem + OFF_XS);
  float* W1s = (float*)(smem + OFF_W1);
  float* s1  = (float*)(smem + OFF_S1);
  float* t1  = (float*)(smem + OFF_T1);

  // ---- stable argsort of node_ids: key = (nid<<11)|idx (nid < 2^20) ----
  for (int i = t; i < NN; i += BLK) keys[i] = ((u32)nidg[i] << 11) | (u32)i;
  __syncthreads();
  bitonic2048(keys, t);
  for (int i = t; i < NN; i += BLK) perm[i] = (u16)(keys[i] & 2047u);

  // ---- degree (self-loop weight 1) + per-dst edge histogram ----
  for (int i = t; i < NN; i += BLK) { dinv[i] = 1.0f; cnt[i] = 0u; }
  __syncthreads();
  for (int e = t; e < EE; e += BLK) {
    int d = eig[EE + e];
    atomicAdd(&dinv[d], ewg[e]);
    atomicAdd(&cnt[d], 1u);
  }
  __syncthreads();
  for (int i = t; i < NN; i += BLK) dinv[i] = rsqrtf(dinv[i]);
  __syncthreads();

  // ---- exclusive scan cnt -> seg ----
  u32 c0 = cnt[4*t], c1 = cnt[4*t+1], c2 = cnt[4*t+2], c3 = cnt[4*t+3];
  u32 p1_ = c0, p2_ = c0 + c1, p3_ = c0 + c1 + c2, tot = p3_ + c3;
  u32* aux = keys;              // keys dead
  aux[t] = tot;
  __syncthreads();
  for (int off = 1; off < BLK; off <<= 1) {
    u32 v = (t >= off) ? aux[t - off] : 0u;
    __syncthreads();
    aux[t] += v;
    __syncthreads();
  }
  u32 base = (t == 0) ? 0u : aux[t - 1];
  seg[4*t] = base; seg[4*t+1] = base + p1_; seg[4*t+2] = base + p2_; seg[4*t+3] = base + p3_;
  if (t == 0) seg[NN] = aux[BLK - 1];
  __syncthreads();
  for (int i = t; i < NN; i += BLK) cnt[i] = seg[i];   // cursor
  // ---- length-balanced dst order (reduce wave divergence in walks) ----
  for (int i = t; i < NN; i += BLK) { u32 len = seg[i+1] - seg[i]; keys[i] = (len << 11) | (u32)i; }
  __syncthreads();
  bitonic2048(keys, t);
  for (int i = t; i < NN; i += BLK) leno[i] = (u16)(keys[i] & 2047u);
  __syncthreads();

  // ---- counting-sort edges by dst into records (src<<16 | f16(norm)) ----
  for (int e = t; e < EE; e += BLK) {
    int s = eig[e], d = eig[EE + e];
    float nrm = dinv[s] * ewg[e] * dinv[d];
    u32 pos = atomicAdd(&cnt[d], 1u);
    __half hh = __float2half(nrm);
    recf[pos] = ((u32)s << 16) | (u32)__half_as_ushort(hh);
  }

  // ---- stage permuted x + layer-1 constants ----
  for (int i = t; i < NN; i += BLK) {
    int p = perm[i];
    const float4* xr = (const float4*)(xg + (size_t)p * FIN);
    float4 a = xr[0], b = xr[1];
    float* o = xs + i * 9;
    o[0]=a.x; o[1]=a.y; o[2]=a.z; o[3]=a.w; o[4]=b.x; o[5]=b.y; o[6]=b.z; o[7]=b.w;
  }
  for (int i = t; i < 512; i += BLK) W1s[i] = W1[i];
  if (t < 64) {
    float sc = g1[t] * rsqrtf(v1[t] + EPS);
    s1[t] = sc;
    t1[t] = (b1[t] - m1[t]) * sc + be1[t];   // fold bias+BN
  }
  __syncthreads();

  // per-thread dst info (cached: LDS metadata gets overwritten in A2)
  int dA[4]; u32 sA[4], eA[4]; float dvA[4];
  #pragma unroll
  for (int it = 0; it < 4; ++it) {
    int d = leno[it * BLK + t];
    dA[it] = d; sA[it] = seg[d]; eA[it] = seg[d + 1]; dvA[it] = dinv[d];
  }

  // ---- layer 1: aggregate x (8-dim), then @W1, BN, ReLU -> h1 (bf16 planes) ----
  for (int it = 0; it < 4; ++it) {
    int d = dA[it];
    float acc[8] = {0,0,0,0,0,0,0,0};
    for (u32 r = sA[it]; r < eA[it]; ++r) {
      u32 rc = recf[r];
      int s = rc >> 16;
      float nrm = __half2float(__ushort_as_half((u16)(rc & 0xFFFFu)));
      const float* xr = xs + s * 9;
      #pragma unroll
      for (int k = 0; k < 8; ++k) acc[k] += nrm * xr[k];
    }
    float dv2 = dvA[it] * dvA[it];
    const float* xd = xs + d * 9;
    #pragma unroll
    for (int k = 0; k < 8; ++k) acc[k] += dv2 * xd[k];
    float z[64];
    #pragma unroll
    for (int j = 0; j < 64; ++j) z[j] = 0.f;
    #pragma unroll
    for (int k = 0; k < 8; ++k) {
      float f = acc[k];
      const float4* wr = (const float4*)(W1s + k * 64);
      #pragma unroll
      for (int q = 0; q < 16; ++q) {
        float4 w = wr[q];
        z[4*q]   += f * w.x; z[4*q+1] += f * w.y;
        z[4*q+2] += f * w.z; z[4*q+3] += f * w.w;
      }
    }
    u32 pk[32];
    #pragma unroll
    for (int q = 0; q < 32; ++q) {
      float h0 = fmaxf(z[2*q]   * s1[2*q]   + t1[2*q],   0.f);
      float h1v = fmaxf(z[2*q+1] * s1[2*q+1] + t1[2*q+1], 0.f);
      pk[q] = pack2bf(h0, h1v);
    }
    uint4* o0 = (uint4*)(h1f + (size_t)d * 32);
    uint4* o1 = (uint4*)(h1f + (size_t)(NN * 32) + (size_t)d * 32);
    o0[0] = make_uint4(pk[0],pk[1],pk[2],pk[3]);
    o0[1] = make_uint4(pk[4],pk[5],pk[6],pk[7]);
    o0[2] = make_uint4(pk[8],pk[9],pk[10],pk[11]);
    o0[3] = make_uint4(pk[12],pk[13],pk[14],pk[15]);
    o1[0] = make_uint4(pk[16],pk[17],pk[18],pk[19]);
    o1[1] = make_uint4(pk[20],pk[21],pk[22],pk[23]);
    o1[2] = make_uint4(pk[24],pk[25],pk[26],pk[27]);
    o1[3] = make_uint4(pk[28],pk[29],pk[30],pk[31]);
  }

  // ---- layer 2 aggregation of h1 (defer @W2 to kernel B); two feature halves ----
  // agg2 output aliases h1f planes (safe: LDS copy loaded + barrier before writes)
  for (int half = 0; half < 2; ++half) {
    __syncthreads();   // all readers of previous LDS contents done
    const uint4* gp = (const uint4*)(h1f + (size_t)half * NN * 32);
    for (int i = t; i < NN * 4; i += BLK) {
      uint4 v = gp[i];
      int row = i >> 2, q = i & 3;
      uint2* lp = (uint2*)(smem + row * 72 + q * 16);   // row stride 36 bf16 = 72B
      lp[0] = make_uint2(v.x, v.y);
      lp[1] = make_uint2(v.z, v.w);
    }
    __syncthreads();
    for (int it = 0; it < 4; ++it) {
      int d = dA[it];
      float acc[32];
      #pragma unroll
      for (int k = 0; k < 32; ++k) acc[k] = 0.f;
      for (u32 r = sA[it]; r < eA[it]; ++r) {
        u32 rc = recf[r];
        int s = rc >> 16;
        float nrm = __half2float(__ushort_as_half((u16)(rc & 0xFFFFu)));
        const uint2* rp = (const uint2*)(smem + s * 72);
        #pragma unroll
        for (int q = 0; q < 8; ++q) {
          uint2 w = rp[q];
          acc[4*q]   += nrm * bflo(w.x);
          acc[4*q+1] += nrm * bfhi(w.x);
          acc[4*q+2] += nrm * bflo(w.y);
          acc[4*q+3] += nrm * bfhi(w.y);
        }
      }
      float dv2 = dvA[it] * dvA[it];
      const uint2* rd = (const uint2*)(smem + d * 72);
      #pragma unroll
      for (int q = 0; q < 8; ++q) {
        uint2 w = rd[q];
        acc[4*q]   += dv2 * bflo(w.x);
        acc[4*q+1] += dv2 * bfhi(w.x);
        acc[4*q+2] += dv2 * bflo(w.y);
        acc[4*q+3] += dv2 * bfhi(w.y);
      }
      u32 pk[16];
      #pragma unroll
      for (int q = 0; q < 16; ++q) pk[q] = pack2bf(acc[2*q], acc[2*q+1]);
      uint4* op = (uint4*)(h1f + (size_t)half * NN * 32 + (size_t)d * 32);
      op[0] = make_uint4(pk[0],pk[1],pk[2],pk[3]);
      op[1] = make_uint4(pk[4],pk[5],pk[6],pk[7]);
      op[2] = make_uint4(pk[8],pk[9],pk[10],pk[11]);
      op[3] = make_uint4(pk[12],pk[13],pk[14],pk[15]);
    }
  }
}

// ---- kernel B: h2 = ReLU(BN(agg2 @ W2 + b2)); frame mean ----
__global__ __launch_bounds__(512, 2) void kB(
    const u16* __restrict__ agg, const float* __restrict__ W2, const float* __restrict__ b2,
    const float* __restrict__ g2, const float* __restrict__ be2,
    const float* __restrict__ m2, const float* __restrict__ v2,
    float* __restrict__ frames)
{
  const int g = blockIdx.x;
  const int tid = threadIdx.x;
  const int lane = tid & 63;
  const int wid = tid >> 6;       // 8 waves
  float w2c[64];
  #pragma unroll
  for (int k = 0; k < 64; ++k) w2c[k] = W2[k * 64 + lane];
  float sc = g2[lane] * rsqrtf(v2[lane] + EPS);
  float tc = (b2[lane] - m2[lane]) * sc + be2[lane];
  const uint4* p0 = (const uint4*)(agg + (size_t)g * NN * 64);
  const uint4* p1 = p0 + NN * 4;
  float macc = 0.f;
  for (int i = 0; i < 256; ++i) {
    int m = wid * 256 + i;
    uint4 a0 = p0[m*4+0], a1 = p0[m*4+1], a2 = p0[m*4+2], a3 = p0[m*4+3];
    uint4 b0 = p1[m*4+0], b1_ = p1[m*4+1], b2_ = p1[m*4+2], b3_ = p1[m*4+3];
    float z = 0.f;
#define ACC4(u, base) \
    z += bflo(u.x)*w2c[base+0] + bfhi(u.x)*w2c[base+1] + bflo(u.y)*w2c[base+2] + bfhi(u.y)*w2c[base+3] \
       + bflo(u.z)*w2c[base+4] + bfhi(u.z)*w2c[base+5] + bflo(u.w)*w2c[base+6] + bfhi(u.w)*w2c[base+7];
    ACC4(a0, 0)  ACC4(a1, 8)  ACC4(a2, 16)  ACC4(a3, 24)
    ACC4(b0, 32) ACC4(b1_, 40) ACC4(b2_, 48) ACC4(b3_, 56)
#undef ACC4
    float h = fmaxf(z * sc + tc, 0.f);
    macc += h;
  }
  __shared__ float part[8][64];
  part[wid][lane] = macc;
  __syncthreads();
  if (tid < 64) {
    float s = 0.f;
    #pragma unroll
    for (int w = 0; w < 8; ++w) s += part[w][tid];
    frames[g * 64 + tid] = s * (1.0f / 2048.0f);
  }
}

// ---- kernel C: GRU over T=30 + classifier; one block per batch element ----
__global__ __launch_bounds__(384, 2) void kC(
    const float* __restrict__ frames,
    const float* __restrict__ Wih, const float* __restrict__ Whh,
    const float* __restrict__ bih, const float* __restrict__ bhh,
    const float* __restrict__ Wc1, const float* __restrict__ bc1,
    const float* __restrict__ Wc2, const float* __restrict__ bc2,
    float* __restrict__ out)
{
  const int b = blockIdx.x;
  const int j = threadIdx.x;     // 384 = 3*TEMP gate rows
  __shared__ float xt[64], h[128], GI[384], GH[384], hid[64];
  float wih[64], whh[128];
  const float4* wi4 = (const float4*)(Wih + (size_t)j * 64);
  #pragma unroll
  for (int q = 0; q < 16; ++q) { float4 v = wi4[q]; wih[4*q]=v.x; wih[4*q+1]=v.y; wih[4*q+2]=v.z; wih[4*q+3]=v.w; }
  const float4* wh4 = (const float4*)(Whh + (size_t)j * 128);
  #pragma unroll
  for (int q = 0; q < 32; ++q) { float4 v = wh4[q]; whh[4*q]=v.x; whh[4*q+1]=v.y; whh[4*q+2]=v.z; whh[4*q+3]=v.w; }
  float bi = bih[j], bh = bhh[j];
  if (j < 128) h[j] = 0.f;
  __syncthreads();
  for (int t = 0; t < T_; ++t) {
    if (j < 64) xt[j] = frames[((size_t)b * T_ + t) * 64 + j];
    __syncthreads();
    float gi = bi, gh = bh;
    #pragma unroll
    for (int k = 0; k < 64; ++k) gi += xt[k] * wih[k];
    #pragma unroll
    for (int k = 0; k < 128; ++k) gh += h[k] * whh[k];
    GI[j] = gi; GH[j] = gh;
    __syncthreads();
    if (j < 128) {
      float r = 1.f / (1.f + __expf(-(GI[j] + GH[j])));
      float z = 1.f / (1.f + __expf(-(GI[128 + j] + GH[128 + j])));
      float n = tanhf(GI[256 + j] + r * GH[256 + j]);
      h[j] = (1.f - z) * n + z * h[j];
    }
    __syncthreads();
  }
  if (j < 64) {
    float a = bc1[j];
    #pragma unroll 4
    for (int k = 0; k < 128; ++k) a += h[k] * Wc1[k * 64 + j];
    hid[j] = fmaxf(a, 0.f);
  }
  __syncthreads();
  if (j < 2) {
    float o = bc2[j];
    #pragma unroll
    for (int k = 0; k < 64; ++k) o += hid[k] * Wc2[k * 2 + j];
    out[b * 2 + j] = o;
  }
}

// ---------- launch ----------
extern "C" void kernel_launch(void* const* d_in, const int* in_sizes, int n_in,
                              void* d_out, int out_size, void* d_ws, size_t ws_size,
                              hipStream_t stream) {
  const float* x   = (const float*)d_in[0];
  const int*   ei  = (const int*)d_in[1];
  const float* ew  = (const float*)d_in[2];
  const int*   nid = (const int*)d_in[3];
  const float* W1  = (const float*)d_in[4];
  const float* b1  = (const float*)d_in[5];
  const float* W2  = (const float*)d_in[6];
  const float* b2  = (const float*)d_in[7];
  const float* g1  = (const float*)d_in[8];
  const float* be1 = (const float*)d_in[9];
  const float* m1  = (const float*)d_in[10];
  const float* v1  = (const float*)d_in[11];
  const float* g2  = (const float*)d_in[12];
  const float* be2 = (const float*)d_in[13];
  const float* m2  = (const float*)d_in[14];
  const float* v2  = (const float*)d_in[15];
  const float* Wih = (const float*)d_in[16];
  const float* Whh = (const float*)d_in[17];
  const float* bih = (const float*)d_in[18];
  const float* bhh = (const float*)d_in[19];
  const float* Wc1 = (const float*)d_in[20];
  const float* bc1 = (const float*)d_in[21];
  const float* Wc2 = (const float*)d_in[22];
  const float* bc2 = (const float*)d_in[23];
  float* out = (float*)d_out;

  // workspace layout (bytes): records | h1/agg2 bf16 planes | frames
  const size_t REC_OFF = 0;                                  // 480*32768*4  = 62,914,560
  const size_t H1_OFF  = 62914560;                           // 480*2048*64*2 = 125,829,120
  const size_t FR_OFF  = 188743680;                          // 480*64*4 = 122,880
  if (ws_size < (size_t)188866560) return;                   // insufficient scratch

  u32* rec   = (u32*)((char*)d_ws + REC_OFF);
  u16* h1    = (u16*)((char*)d_ws + H1_OFF);
  float* frm = (float*)((char*)d_ws + FR_OFF);

  hipFuncSetAttribute((const void*)kA, hipFuncAttributeMaxDynamicSharedMemorySize, LDS_A);

  kA<<<NF, BLK, LDS_A, stream>>>(x, ei, ew, nid, W1, b1, g1, be1, m1, v1, rec, h1);
  kB<<<NF, 512, 0, stream>>>(h1, W2, b2, g2, be2, m2, v2, frm);
  kC<<<B_, 384, 0, stream>>>(frm, Wih, Whh, bih, bhh, Wc1, bc1, Wc2, bc2, out);
}